// Round 9
// baseline (177.403 us; speedup 1.0000x reference)
//
#include <hip/hip_runtime.h>

typedef __attribute__((ext_vector_type(8))) short short8;
typedef __attribute__((ext_vector_type(4))) float f32x4;

#define MFMA(a,b,c) __builtin_amdgcn_mfma_f32_16x16x32_bf16((a),(b),(c),0,0,0)

#define B_  2
#define S_  2048
#define D_  1024
#define H_  16
#define DK  64
#define KDIM 1024

typedef unsigned int u32;
typedef __attribute__((address_space(1))) const u32 gu32;
typedef __attribute__((address_space(3))) u32 lu32;

// async global->LDS, 16 B per lane; LDS dest = base + lane*16 (wave-uniform base)
__device__ __forceinline__ void gll16(const unsigned short* g, unsigned short* l){
  __builtin_amdgcn_global_load_lds((gu32*)g, (lu32*)l, 16, 0, 0);
}

__device__ __forceinline__ unsigned short f2bf(float f){
  unsigned int u = __float_as_uint(f);
  u += 0x7fffu + ((u >> 16) & 1u);   // RNE (finite inputs only)
  return (unsigned short)(u >> 16);
}

// pack two f32 -> two bf16 (round-half-up) in 3 VALU: 2 adds + v_perm_b32.
__device__ __forceinline__ u32 pkbf(float lo, float hi){
  u32 a = __float_as_uint(lo) + 0x8000u;
  u32 b = __float_as_uint(hi) + 0x8000u;
  return __builtin_amdgcn_perm(b, a, 0x07060302u);
}

// ---------------- fp32 -> bf16 convert, all 5 tensors in one launch ---------
__global__ void cvt_all(const float* __restrict__ x,  const float* __restrict__ qw,
                        const float* __restrict__ kw, const float* __restrict__ vw,
                        const float* __restrict__ ow,
                        unsigned short* __restrict__ xb,  unsigned short* __restrict__ wqb,
                        unsigned short* __restrict__ wkb, unsigned short* __restrict__ wvb,
                        unsigned short* __restrict__ wob,
                        int n4x, int n4w){
  int i = blockIdx.x * 256 + threadIdx.x;
  const float* src; unsigned short* dst; int n4;
  switch (blockIdx.y) {
    case 0:  src = x;  dst = xb;  n4 = n4x; break;
    case 1:  src = qw; dst = wqb; n4 = n4w; break;
    case 2:  src = kw; dst = wkb; n4 = n4w; break;
    case 3:  src = vw; dst = wvb; n4 = n4w; break;
    default: src = ow; dst = wob; n4 = n4w; break;
  }
  if (i >= n4) return;
  float4 f = reinterpret_cast<const float4*>(src)[i];
  ushort4 u;
  u.x = f2bf(f.x); u.y = f2bf(f.y); u.z = f2bf(f.z); u.w = f2bf(f.w);
  reinterpret_cast<ushort4*>(dst)[i] = u;
}

// ---------------- fused QKV projection (128x64 tile, static dbuf) -----------
// C[m,n] = sum_k X[m,k] * W[n,k];  z=0 -> Q (scaled); z=1 -> K; z=2 -> V^T.
// Ping-pong BK=32 sets with STATIC addressing (R6's dynamic-index dbuf
// regressed on VALU): barrier -> issue next set's loads -> 16 MFMAs from the
// ready set -> the vmcnt(0)-before-barrier drain now follows real compute.
__global__ __launch_bounds__(256) void gemm_qkv(
    const unsigned short* __restrict__ X,
    const unsigned short* __restrict__ Wq,
    const unsigned short* __restrict__ Wk,
    const unsigned short* __restrict__ Wv,
    unsigned short* __restrict__ Qo,
    unsigned short* __restrict__ Ko,
    unsigned short* __restrict__ Vo)
{
  const int z = blockIdx.z;
  const unsigned short* __restrict__ W = (z == 0) ? Wq : (z == 1) ? Wk : Wv;
  const int n0 = blockIdx.x * 64;
  const int m0 = blockIdx.y * 128;

  __shared__ unsigned short As0[128 * 32];
  __shared__ unsigned short As1[128 * 32];
  __shared__ unsigned short Bs0[64 * 32];
  __shared__ unsigned short Bs1[64 * 32];

  const int tid  = threadIdx.x;
  const int wid  = tid >> 6, lane = tid & 63;
  const int wm   = (wid >> 1) * 64, wn = (wid & 1) * 32;
  const int lr   = lane & 15, lk = (lane >> 4) * 8;

  const int srow = lane >> 2;            // 0..15
  const int scol = (lane & 3) * 8;       // shorts
  const unsigned short* gA = X + (size_t)(m0 + wid * 32 + srow) * KDIM + scol;
  const unsigned short* gB = W + (size_t)(n0 + wid * 16 + srow) * KDIM + scol;
  unsigned short* lA0 = &As0[(wid * 32) * 32];
  unsigned short* lA1 = &As1[(wid * 32) * 32];
  unsigned short* lB0 = &Bs0[(wid * 16) * 32];
  unsigned short* lB1 = &Bs1[(wid * 16) * 32];

  f32x4 acc[4][2];
  const f32x4 z4 = {0.f, 0.f, 0.f, 0.f};
  for (int i = 0; i < 4; i++)
    for (int j = 0; j < 2; j++) acc[i][j] = z4;

  auto compute = [&](const unsigned short* AS, const unsigned short* BS){
    short8 a[4], b[2];
    for (int i = 0; i < 4; i++) a[i] = *(const short8*)&AS[(wm + i * 16 + lr) * 32 + lk];
    for (int j = 0; j < 2; j++) b[j] = *(const short8*)&BS[(wn + j * 16 + lr) * 32 + lk];
    if (z == 2) {
      for (int i = 0; i < 4; i++)
        for (int j = 0; j < 2; j++)
          acc[i][j] = MFMA(b[j], a[i], acc[i][j]);   // rows=W-dim, cols=X-dim
    } else {
      for (int i = 0; i < 4; i++)
        for (int j = 0; j < 2; j++)
          acc[i][j] = MFMA(a[i], b[j], acc[i][j]);
    }
  };

  // prologue: k=0 into set0
  gll16(gA,             lA0);
  gll16(gA + 16 * KDIM, lA0 + 16 * 32);
  gll16(gB,             lB0);

  for (int k0 = 0; k0 < KDIM; k0 += 64) {
    __syncthreads();                       // set0 (k0) ready
    {
      const int kn = k0 + 32;              // always < KDIM
      gll16(gA + kn,             lA1);
      gll16(gA + 16 * KDIM + kn, lA1 + 16 * 32);
      gll16(gB + kn,             lB1);
    }
    compute(As0, Bs0);
    __syncthreads();                       // set1 (k0+32) ready
    if (k0 + 64 < KDIM) {
      const int kn = k0 + 64;
      gll16(gA + kn,             lA0);
      gll16(gA + 16 * KDIM + kn, lA0 + 16 * 32);
      gll16(gB + kn,             lB0);
    }
    compute(As1, Bs1);
  }

  const int rbase = (lane >> 4) * 4;
  if (z == 2) {
    for (int i = 0; i < 4; i++)
      for (int j = 0; j < 2; j++)
        for (int r = 0; r < 4; r++) {
          int dfull = n0 + wn + j * 16 + rbase + r;   // W row (h,dk)
          int sfull = m0 + wm + i * 16 + lr;          // X row (b,s)
          int h = dfull >> 6, d = dfull & 63;
          int bb = sfull >> 11, s = sfull & 2047;
          Vo[(((bb * H_ + h) * DK) + d) * S_ + s] = f2bf(acc[i][j][r]);
        }
  } else {
    for (int i = 0; i < 4; i++)
      for (int j = 0; j < 2; j++)
        for (int r = 0; r < 4; r++) {
          int m = m0 + wm + i * 16 + rbase + r;
          int n = n0 + wn + j * 16 + lr;
          float v = acc[i][j][r];
          int bb = m >> 11, s = m & 2047, h = n >> 6, d = n & 63;
          if (z == 0) {
            v *= 0.18033688f;  // (1/sqrt(64)) * log2(e): softmax in exp2 domain
            Qo[(((bb * H_ + h) * S_) + s) * DK + d] = f2bf(v);
          } else {
            Ko[(((bb * H_ + h) * S_) + s) * DK + d] = f2bf(v);
          }
        }
  }
}

// ---------------- causal flash attention (512 thr, gll16 + swizzle dbuf) ----
// Q,K: [B,H,S,DK] bf16 (Q pre-scaled to exp2 domain); V: [B,H,DK,S] bf16.
// K/V staged via global_load_lds into UNPADDED 64x64 tiles with a rotation
// swizzle: physical 16B-chunk c of row r holds logical chunk (c-r)&7, so
// ds_read_b128 banks stay balanced and the read offset is a lane-constant.
// Ping-pong buffers, 1 barrier per tile (was 2), no reg round-trip.
__global__ __launch_bounds__(512, 4) void attn(
    const unsigned short* __restrict__ Q,
    const unsigned short* __restrict__ K,
    const unsigned short* __restrict__ V,
    unsigned short* __restrict__ O)
{
  const int h = blockIdx.y, b = blockIdx.z;
  const int qt = b ? (15 - blockIdx.x) : blockIdx.x;

  const unsigned short* __restrict__ Qh = Q + (size_t)((b * H_ + h) * S_) * DK;
  const unsigned short* __restrict__ Kh = K + (size_t)((b * H_ + h) * S_) * DK;
  const unsigned short* __restrict__ Vh = V + (size_t)((b * H_ + h) * DK) * S_;

  __shared__ unsigned short Ks0[64 * 64];     // [key][d], swizzled chunks
  __shared__ unsigned short Ks1[64 * 64];
  __shared__ unsigned short Vs0[64 * 64];     // [d][key], swizzled chunks
  __shared__ unsigned short Vs1[64 * 64];
  __shared__ unsigned short Ps[8][16][72];    // per-wave: [q][key] (padded)

  const int tid = threadIdx.x, wid = tid >> 6, lane = tid & 63;
  const int lr = lane & 15;
  const int row4 = (lane >> 4) * 4;
  const int q0 = qt * 128;
  const int qcol = q0 + wid * 16 + lr;
  const int qwmin = q0 + wid * 16;
  const int qwmax = qwmin + 15;
  const int lk = (lane >> 4) * 8;             // for Q/P fragments (unswizzled)

  // swizzled LDS read offsets (shorts): logical chunk q=(lane>>4), rot by row
  const int pc0 = (((lane >> 4) + lr) & 7) * 8;
  const int pc1 = (((lane >> 4) + 4 + lr) & 7) * 8;

  // staging: wave wid covers rows [8*wid, 8*wid+8) of both K and V tiles
  const int sr8 = lane >> 3;                  // 0..7 row within chunk
  const int sc8 = lane & 7;                   // physical chunk
  const int sg  = (sc8 - sr8) & 7;            // logical chunk to fetch
  const int stRow = wid * 8 + sr8;            // 0..63
  const unsigned short* gK = Kh + (size_t)stRow * DK + sg * 8;
  const unsigned short* gV = Vh + (size_t)stRow * S_ + sg * 8;
  unsigned short* lK0 = &Ks0[wid * 8 * 64];
  unsigned short* lK1 = &Ks1[wid * 8 * 64];
  unsigned short* lV0 = &Vs0[wid * 8 * 64];
  unsigned short* lV1 = &Vs1[wid * 8 * 64];

  const short ONE = (short)0x3F80;            // bf16 1.0
  const short8 ones = {ONE, ONE, ONE, ONE, ONE, ONE, ONE, ONE};

  short8 qf[2];
  qf[0] = *(const short8*)&Qh[(q0 + wid * 16 + lr) * DK + lk];
  qf[1] = *(const short8*)&Qh[(q0 + wid * 16 + lr) * DK + 32 + lk];

  const f32x4 z4 = {0.f, 0.f, 0.f, 0.f};
  f32x4 o[4];
  for (int i = 0; i < 4; i++) o[i] = z4;
  f32x4 rs = z4;                              // l(q=lr) on the MFMA pipe

  auto tile = [&](int k0, const unsigned short* KS, const unsigned short* VS){
    if (k0 > qwmax) return;                   // wave-uniform skip
    f32x4 sc[4];
    for (int nt = 0; nt < 4; nt++) {
      short8 kb0 = *(const short8*)&KS[(nt * 16 + lr) * 64 + pc0];
      short8 kb1 = *(const short8*)&KS[(nt * 16 + lr) * 64 + pc1];
      f32x4 s = MFMA(kb0, qf[0], z4);
      sc[nt] = MFMA(kb1, qf[1], s);
    }
    if (k0 + 63 > qwmin) {                    // diagonal region: mask key > q
      for (int nt = 0; nt < 4; nt++) {
        int kg = k0 + nt * 16 + row4;
        for (int r = 0; r < 4; r++)
          if (kg + r > qcol) sc[nt][r] = -INFINITY;
      }
    }
    for (int nt = 0; nt < 4; nt++) {
      float p0 = __builtin_amdgcn_exp2f(sc[nt][0]);
      float p1 = __builtin_amdgcn_exp2f(sc[nt][1]);
      float p2 = __builtin_amdgcn_exp2f(sc[nt][2]);
      float p3 = __builtin_amdgcn_exp2f(sc[nt][3]);
      uint2 pk;
      pk.x = pkbf(p0, p1);
      pk.y = pkbf(p2, p3);
      *(uint2*)&Ps[wid][lr][nt * 16 + row4] = pk;
    }
    short8 pf0 = *(const short8*)&Ps[wid][lr][lk];
    short8 pf1 = *(const short8*)&Ps[wid][lr][32 + lk];
    rs = MFMA(ones, pf0, rs);
    rs = MFMA(ones, pf1, rs);
    for (int dt = 0; dt < 4; dt++) {
      short8 vb0 = *(const short8*)&VS[(dt * 16 + lr) * 64 + pc0];
      short8 vb1 = *(const short8*)&VS[(dt * 16 + lr) * 64 + pc1];
      o[dt] = MFMA(vb0, pf0, o[dt]);
      o[dt] = MFMA(vb1, pf1, o[dt]);
    }
  };

  const int kt_end = 2 * qt + 2;              // even

  // prologue: tile 0 into buf0
  gll16(gK, lK0);
  gll16(gV, lV0);

  for (int kt = 0; kt < kt_end; kt += 2) {
    const int k0 = kt * 64;
    __syncthreads();                          // buf0 (k0) ready
    {                                         // kt+1 always < kt_end
      gll16(gK + (size_t)(k0 + 64) * DK, lK1);
      gll16(gV + (k0 + 64),              lV1);
    }
    tile(k0, Ks0, Vs0);
    __syncthreads();                          // buf1 (k0+64) ready
    if (kt + 2 < kt_end) {
      gll16(gK + (size_t)(k0 + 128) * DK, lK0);
      gll16(gV + (k0 + 128),              lV0);
    }
    tile(k0 + 64, Ks1, Vs1);
  }

  const float inv = 1.0f / rs[0];

  const int srow = q0 + wid * 16 + lr;
  for (int dt = 0; dt < 4; dt++) {
    uint2 pk;
    pk.x = pkbf(o[dt][0] * inv, o[dt][1] * inv);
    pk.y = pkbf(o[dt][2] * inv, o[dt][3] * inv);
    *(uint2*)&O[(size_t)(b * S_ + srow) * D_ + h * DK + dt * 16 + row4] = pk;
  }
}

// ---------------- output projection (fp32 out, 128x64, static dbuf) ---------
__global__ __launch_bounds__(256) void gemm_oproj(
    const unsigned short* __restrict__ A,
    const unsigned short* __restrict__ W,
    float* __restrict__ out)
{
  const int n0 = blockIdx.x * 64;
  const int m0 = blockIdx.y * 128;

  __shared__ unsigned short As0[128 * 32];
  __shared__ unsigned short As1[128 * 32];
  __shared__ unsigned short Bs0[64 * 32];
  __shared__ unsigned short Bs1[64 * 32];

  const int tid  = threadIdx.x;
  const int wid  = tid >> 6, lane = tid & 63;
  const int wm   = (wid >> 1) * 64, wn = (wid & 1) * 32;
  const int lr   = lane & 15, lk = (lane >> 4) * 8;

  const int srow = lane >> 2;
  const int scol = (lane & 3) * 8;
  const unsigned short* gA = A + (size_t)(m0 + wid * 32 + srow) * KDIM + scol;
  const unsigned short* gB = W + (size_t)(n0 + wid * 16 + srow) * KDIM + scol;
  unsigned short* lA0 = &As0[(wid * 32) * 32];
  unsigned short* lA1 = &As1[(wid * 32) * 32];
  unsigned short* lB0 = &Bs0[(wid * 16) * 32];
  unsigned short* lB1 = &Bs1[(wid * 16) * 32];

  f32x4 acc[4][2];
  const f32x4 z4 = {0.f, 0.f, 0.f, 0.f};
  for (int i = 0; i < 4; i++)
    for (int j = 0; j < 2; j++) acc[i][j] = z4;

  auto compute = [&](const unsigned short* AS, const unsigned short* BS){
    short8 a[4], b[2];
    for (int i = 0; i < 4; i++) a[i] = *(const short8*)&AS[(wm + i * 16 + lr) * 32 + lk];
    for (int j = 0; j < 2; j++) b[j] = *(const short8*)&BS[(wn + j * 16 + lr) * 32 + lk];
    for (int i = 0; i < 4; i++)
      for (int j = 0; j < 2; j++)
        acc[i][j] = MFMA(a[i], b[j], acc[i][j]);
  };

  gll16(gA,             lA0);
  gll16(gA + 16 * KDIM, lA0 + 16 * 32);
  gll16(gB,             lB0);

  for (int k0 = 0; k0 < KDIM; k0 += 64) {
    __syncthreads();
    {
      const int kn = k0 + 32;
      gll16(gA + kn,             lA1);
      gll16(gA + 16 * KDIM + kn, lA1 + 16 * 32);
      gll16(gB + kn,             lB1);
    }
    compute(As0, Bs0);
    __syncthreads();
    if (k0 + 64 < KDIM) {
      const int kn = k0 + 64;
      gll16(gA + kn,             lA0);
      gll16(gA + 16 * KDIM + kn, lA0 + 16 * 32);
      gll16(gB + kn,             lB0);
    }
    compute(As1, Bs1);
  }

  const int rbase = (lane >> 4) * 4;
  for (int i = 0; i < 4; i++)
    for (int j = 0; j < 2; j++)
      for (int r = 0; r < 4; r++) {
        int m = m0 + wm + i * 16 + rbase + r;
        int n = n0 + wn + j * 16 + lr;
        out[(size_t)m * D_ + n] = acc[i][j][r];
      }
}

extern "C" void kernel_launch(void* const* d_in, const int* in_sizes, int n_in,
                              void* d_out, int out_size, void* d_ws, size_t ws_size,
                              hipStream_t stream) {
  const float* x  = (const float*)d_in[0];
  const float* qw = (const float*)d_in[1];
  const float* kw = (const float*)d_in[2];
  const float* vw = (const float*)d_in[3];
  const float* ow = (const float*)d_in[4];
  float* out = (float*)d_out;

  char* ws = (char*)d_ws;
  size_t off = 0;
  auto alloc = [&](size_t bytes) -> void* {
    void* p = ws + off;
    off += (bytes + 255) & ~(size_t)255;
    return p;
  };
  const size_t XN = (size_t)B_ * S_ * D_;     // 4194304
  const size_t WN = (size_t)D_ * D_;          // 1048576
  unsigned short* xb  = (unsigned short*)alloc(XN * 2);
  unsigned short* wqb = (unsigned short*)alloc(WN * 2);
  unsigned short* wkb = (unsigned short*)alloc(WN * 2);
  unsigned short* wvb = (unsigned short*)alloc(WN * 2);
  unsigned short* wob = (unsigned short*)alloc(WN * 2);
  unsigned short* Qb  = (unsigned short*)alloc(XN * 2);
  unsigned short* Kb  = (unsigned short*)alloc(XN * 2);
  unsigned short* Vb  = (unsigned short*)alloc(XN * 2);
  unsigned short* Ob  = (unsigned short*)alloc(XN * 2);

  cvt_all<<<dim3((XN / 4 + 255) / 256, 5), dim3(256), 0, stream>>>(
      x, qw, kw, vw, ow, xb, wqb, wkb, wvb, wob, (int)(XN / 4), (int)(WN / 4));

  gemm_qkv<<<dim3(D_ / 64, (B_ * S_) / 128, 3), dim3(256), 0, stream>>>(
      xb, wqb, wkb, wvb, Qb, Kb, Vb);

  attn<<<dim3(S_ / 128, H_, B_), dim3(512), 0, stream>>>(Qb, Kb, Vb, Ob);

  gemm_oproj<<<dim3(D_ / 64, (B_ * S_) / 128), dim3(256), 0, stream>>>(Ob, wob, out);
}

// Round 10
// 173.319 us; speedup vs baseline: 1.0236x; 1.0236x over previous
//
#include <hip/hip_runtime.h>

typedef __attribute__((ext_vector_type(8))) short short8;
typedef __attribute__((ext_vector_type(4))) float f32x4;

#define MFMA(a,b,c) __builtin_amdgcn_mfma_f32_16x16x32_bf16((a),(b),(c),0,0,0)

#define B_  2
#define S_  2048
#define D_  1024
#define H_  16
#define DK  64
#define KDIM 1024

typedef unsigned int u32;
typedef __attribute__((address_space(1))) const u32 gu32;
typedef __attribute__((address_space(3))) u32 lu32;

// async global->LDS, 16 B per lane; LDS dest = base + lane*16 (wave-uniform base)
__device__ __forceinline__ void gll16(const unsigned short* g, unsigned short* l){
  __builtin_amdgcn_global_load_lds((gu32*)g, (lu32*)l, 16, 0, 0);
}

__device__ __forceinline__ unsigned short f2bf(float f){
  unsigned int u = __float_as_uint(f);
  u += 0x7fffu + ((u >> 16) & 1u);   // RNE (finite inputs only)
  return (unsigned short)(u >> 16);
}

// pack two f32 -> two bf16 (round-half-up) in 3 VALU: 2 adds + v_perm_b32.
__device__ __forceinline__ u32 pkbf(float lo, float hi){
  u32 a = __float_as_uint(lo) + 0x8000u;
  u32 b = __float_as_uint(hi) + 0x8000u;
  return __builtin_amdgcn_perm(b, a, 0x07060302u);
}

// ---------------- fp32 -> bf16 convert, all 5 tensors in one launch ---------
__global__ void cvt_all(const float* __restrict__ x,  const float* __restrict__ qw,
                        const float* __restrict__ kw, const float* __restrict__ vw,
                        const float* __restrict__ ow,
                        unsigned short* __restrict__ xb,  unsigned short* __restrict__ wqb,
                        unsigned short* __restrict__ wkb, unsigned short* __restrict__ wvb,
                        unsigned short* __restrict__ wob,
                        int n4x, int n4w){
  int i = blockIdx.x * 256 + threadIdx.x;
  const float* src; unsigned short* dst; int n4;
  switch (blockIdx.y) {
    case 0:  src = x;  dst = xb;  n4 = n4x; break;
    case 1:  src = qw; dst = wqb; n4 = n4w; break;
    case 2:  src = kw; dst = wkb; n4 = n4w; break;
    case 3:  src = vw; dst = wvb; n4 = n4w; break;
    default: src = ow; dst = wob; n4 = n4w; break;
  }
  if (i >= n4) return;
  float4 f = reinterpret_cast<const float4*>(src)[i];
  ushort4 u;
  u.x = f2bf(f.x); u.y = f2bf(f.y); u.z = f2bf(f.z); u.w = f2bf(f.w);
  reinterpret_cast<ushort4*>(dst)[i] = u;
}

// ---------------- fused QKV projection (128x64, R8 batch-issue staging) -----
// C[m,n] = sum_k X[m,k] * W[n,k];  z=0 -> Q (scaled); z=1 -> K; z=2 -> V^T.
// Batch-issue: all 6 global_load_lds back-to-back, ONE drain per 64-K window.
// (Interleaved prefetch regressed twice: with compute C << latency L, each
// extra barrier pays max(0, L-C) -> 2 partial drains > 1 full drain.)
__global__ __launch_bounds__(256) void gemm_qkv(
    const unsigned short* __restrict__ X,
    const unsigned short* __restrict__ Wq,
    const unsigned short* __restrict__ Wk,
    const unsigned short* __restrict__ Wv,
    unsigned short* __restrict__ Qo,
    unsigned short* __restrict__ Ko,
    unsigned short* __restrict__ Vo)
{
  const int z = blockIdx.z;
  const unsigned short* __restrict__ W = (z == 0) ? Wq : (z == 1) ? Wk : Wv;
  const int n0 = blockIdx.x * 64;
  const int m0 = blockIdx.y * 128;

  __shared__ unsigned short As0[128 * 32];
  __shared__ unsigned short As1[128 * 32];
  __shared__ unsigned short Bs0[64 * 32];
  __shared__ unsigned short Bs1[64 * 32];

  const int tid  = threadIdx.x;
  const int wid  = tid >> 6, lane = tid & 63;
  const int wm   = (wid >> 1) * 64, wn = (wid & 1) * 32;
  const int lr   = lane & 15, lk = (lane >> 4) * 8;

  const int srow = lane >> 2;            // 0..15
  const int scol = (lane & 3) * 8;       // shorts
  const unsigned short* gA = X + (size_t)(m0 + wid * 32 + srow) * KDIM + scol;
  const unsigned short* gB = W + (size_t)(n0 + wid * 16 + srow) * KDIM + scol;
  unsigned short* lA0 = &As0[(wid * 32) * 32];
  unsigned short* lA1 = &As1[(wid * 32) * 32];
  unsigned short* lB0 = &Bs0[(wid * 16) * 32];
  unsigned short* lB1 = &Bs1[(wid * 16) * 32];

  f32x4 acc[4][2];
  const f32x4 z4 = {0.f, 0.f, 0.f, 0.f};
  for (int i = 0; i < 4; i++)
    for (int j = 0; j < 2; j++) acc[i][j] = z4;

  for (int k0 = 0; k0 < KDIM; k0 += 64) {
    __syncthreads();
    gll16(gA + k0,                  lA0);
    gll16(gA + 16 * KDIM + k0,      lA0 + 16 * 32);
    gll16(gA + k0 + 32,             lA1);
    gll16(gA + 16 * KDIM + k0 + 32, lA1 + 16 * 32);
    gll16(gB + k0,                  lB0);
    gll16(gB + k0 + 32,             lB1);
    __syncthreads();

    short8 a[4], b[2];
    // k-half 0
    for (int i = 0; i < 4; i++) a[i] = *(const short8*)&As0[(wm + i * 16 + lr) * 32 + lk];
    for (int j = 0; j < 2; j++) b[j] = *(const short8*)&Bs0[(wn + j * 16 + lr) * 32 + lk];
    if (z == 2) {
      for (int i = 0; i < 4; i++)
        for (int j = 0; j < 2; j++)
          acc[i][j] = MFMA(b[j], a[i], acc[i][j]);   // rows=W-dim, cols=X-dim
    } else {
      for (int i = 0; i < 4; i++)
        for (int j = 0; j < 2; j++)
          acc[i][j] = MFMA(a[i], b[j], acc[i][j]);
    }
    // k-half 1
    for (int i = 0; i < 4; i++) a[i] = *(const short8*)&As1[(wm + i * 16 + lr) * 32 + lk];
    for (int j = 0; j < 2; j++) b[j] = *(const short8*)&Bs1[(wn + j * 16 + lr) * 32 + lk];
    if (z == 2) {
      for (int i = 0; i < 4; i++)
        for (int j = 0; j < 2; j++)
          acc[i][j] = MFMA(b[j], a[i], acc[i][j]);
    } else {
      for (int i = 0; i < 4; i++)
        for (int j = 0; j < 2; j++)
          acc[i][j] = MFMA(a[i], b[j], acc[i][j]);
    }
  }

  const int rbase = (lane >> 4) * 4;
  if (z == 2) {
    for (int i = 0; i < 4; i++)
      for (int j = 0; j < 2; j++)
        for (int r = 0; r < 4; r++) {
          int dfull = n0 + wn + j * 16 + rbase + r;   // W row (h,dk)
          int sfull = m0 + wm + i * 16 + lr;          // X row (b,s)
          int h = dfull >> 6, d = dfull & 63;
          int bb = sfull >> 11, s = sfull & 2047;
          Vo[(((bb * H_ + h) * DK) + d) * S_ + s] = f2bf(acc[i][j][r]);
        }
  } else {
    for (int i = 0; i < 4; i++)
      for (int j = 0; j < 2; j++)
        for (int r = 0; r < 4; r++) {
          int m = m0 + wm + i * 16 + rbase + r;
          int n = n0 + wn + j * 16 + lr;
          float v = acc[i][j][r];
          int bb = m >> 11, s = m & 2047, h = n >> 6, d = n & 63;
          if (z == 0) {
            v *= 0.18033688f;  // (1/sqrt(64)) * log2(e): softmax in exp2 domain
            Qo[(((bb * H_ + h) * S_) + s) * DK + d] = f2bf(v);
          } else {
            Ko[(((bb * H_ + h) * S_) + s) * DK + d] = f2bf(v);
          }
        }
  }
}

// ---------------- causal flash attention (R9 structure, kept) ---------------
// Q,K: [B,H,S,DK] bf16 (Q pre-scaled to exp2 domain); V: [B,H,DK,S] bf16.
// K/V staged via global_load_lds into UNPADDED 64x64 tiles with a rotation
// swizzle: physical 16B-chunk c of row r holds logical chunk (c-r)&7.
// Ping-pong buffers, 1 barrier per tile, no reg round-trip.
__global__ __launch_bounds__(512, 4) void attn(
    const unsigned short* __restrict__ Q,
    const unsigned short* __restrict__ K,
    const unsigned short* __restrict__ V,
    unsigned short* __restrict__ O)
{
  const int h = blockIdx.y, b = blockIdx.z;
  const int qt = b ? (15 - blockIdx.x) : blockIdx.x;

  const unsigned short* __restrict__ Qh = Q + (size_t)((b * H_ + h) * S_) * DK;
  const unsigned short* __restrict__ Kh = K + (size_t)((b * H_ + h) * S_) * DK;
  const unsigned short* __restrict__ Vh = V + (size_t)((b * H_ + h) * DK) * S_;

  __shared__ unsigned short Ks0[64 * 64];     // [key][d], swizzled chunks
  __shared__ unsigned short Ks1[64 * 64];
  __shared__ unsigned short Vs0[64 * 64];     // [d][key], swizzled chunks
  __shared__ unsigned short Vs1[64 * 64];
  __shared__ unsigned short Ps[8][16][72];    // per-wave: [q][key] (padded)

  const int tid = threadIdx.x, wid = tid >> 6, lane = tid & 63;
  const int lr = lane & 15;
  const int row4 = (lane >> 4) * 4;
  const int q0 = qt * 128;
  const int qcol = q0 + wid * 16 + lr;
  const int qwmin = q0 + wid * 16;
  const int qwmax = qwmin + 15;
  const int lk = (lane >> 4) * 8;             // for Q/P fragments (unswizzled)

  // swizzled LDS read offsets (shorts): logical chunk q=(lane>>4), rot by row
  const int pc0 = (((lane >> 4) + lr) & 7) * 8;
  const int pc1 = (((lane >> 4) + 4 + lr) & 7) * 8;

  // staging: wave wid covers rows [8*wid, 8*wid+8) of both K and V tiles
  const int sr8 = lane >> 3;                  // 0..7 row within chunk
  const int sc8 = lane & 7;                   // physical chunk
  const int sg  = (sc8 - sr8) & 7;            // logical chunk to fetch
  const int stRow = wid * 8 + sr8;            // 0..63
  const unsigned short* gK = Kh + (size_t)stRow * DK + sg * 8;
  const unsigned short* gV = Vh + (size_t)stRow * S_ + sg * 8;
  unsigned short* lK0 = &Ks0[wid * 8 * 64];
  unsigned short* lK1 = &Ks1[wid * 8 * 64];
  unsigned short* lV0 = &Vs0[wid * 8 * 64];
  unsigned short* lV1 = &Vs1[wid * 8 * 64];

  const short ONE = (short)0x3F80;            // bf16 1.0
  const short8 ones = {ONE, ONE, ONE, ONE, ONE, ONE, ONE, ONE};

  short8 qf[2];
  qf[0] = *(const short8*)&Qh[(q0 + wid * 16 + lr) * DK + lk];
  qf[1] = *(const short8*)&Qh[(q0 + wid * 16 + lr) * DK + 32 + lk];

  const f32x4 z4 = {0.f, 0.f, 0.f, 0.f};
  f32x4 o[4];
  for (int i = 0; i < 4; i++) o[i] = z4;
  f32x4 rs = z4;                              // l(q=lr) on the MFMA pipe

  auto tile = [&](int k0, const unsigned short* KS, const unsigned short* VS){
    if (k0 > qwmax) return;                   // wave-uniform skip
    f32x4 sc[4];
    for (int nt = 0; nt < 4; nt++) {
      short8 kb0 = *(const short8*)&KS[(nt * 16 + lr) * 64 + pc0];
      short8 kb1 = *(const short8*)&KS[(nt * 16 + lr) * 64 + pc1];
      f32x4 s = MFMA(kb0, qf[0], z4);
      sc[nt] = MFMA(kb1, qf[1], s);
    }
    if (k0 + 63 > qwmin) {                    // diagonal region: mask key > q
      for (int nt = 0; nt < 4; nt++) {
        int kg = k0 + nt * 16 + row4;
        for (int r = 0; r < 4; r++)
          if (kg + r > qcol) sc[nt][r] = -INFINITY;
      }
    }
    for (int nt = 0; nt < 4; nt++) {
      float p0 = __builtin_amdgcn_exp2f(sc[nt][0]);
      float p1 = __builtin_amdgcn_exp2f(sc[nt][1]);
      float p2 = __builtin_amdgcn_exp2f(sc[nt][2]);
      float p3 = __builtin_amdgcn_exp2f(sc[nt][3]);
      uint2 pk;
      pk.x = pkbf(p0, p1);
      pk.y = pkbf(p2, p3);
      *(uint2*)&Ps[wid][lr][nt * 16 + row4] = pk;
    }
    short8 pf0 = *(const short8*)&Ps[wid][lr][lk];
    short8 pf1 = *(const short8*)&Ps[wid][lr][32 + lk];
    rs = MFMA(ones, pf0, rs);
    rs = MFMA(ones, pf1, rs);
    for (int dt = 0; dt < 4; dt++) {
      short8 vb0 = *(const short8*)&VS[(dt * 16 + lr) * 64 + pc0];
      short8 vb1 = *(const short8*)&VS[(dt * 16 + lr) * 64 + pc1];
      o[dt] = MFMA(vb0, pf0, o[dt]);
      o[dt] = MFMA(vb1, pf1, o[dt]);
    }
  };

  const int kt_end = 2 * qt + 2;              // even

  // prologue: tile 0 into buf0
  gll16(gK, lK0);
  gll16(gV, lV0);

  for (int kt = 0; kt < kt_end; kt += 2) {
    const int k0 = kt * 64;
    __syncthreads();                          // buf0 (k0) ready
    {                                         // kt+1 always < kt_end
      gll16(gK + (size_t)(k0 + 64) * DK, lK1);
      gll16(gV + (k0 + 64),              lV1);
    }
    tile(k0, Ks0, Vs0);
    __syncthreads();                          // buf1 (k0+64) ready
    if (kt + 2 < kt_end) {
      gll16(gK + (size_t)(k0 + 128) * DK, lK0);
      gll16(gV + (k0 + 128),              lV0);
    }
    tile(k0 + 64, Ks1, Vs1);
  }

  const float inv = 1.0f / rs[0];

  const int srow = q0 + wid * 16 + lr;
  for (int dt = 0; dt < 4; dt++) {
    uint2 pk;
    pk.x = pkbf(o[dt][0] * inv, o[dt][1] * inv);
    pk.y = pkbf(o[dt][2] * inv, o[dt][3] * inv);
    *(uint2*)&O[(size_t)(b * S_ + srow) * D_ + h * DK + dt * 16 + row4] = pk;
  }
}

// ---------------- output projection (fp32 out, R8 batch-issue staging) ------
__global__ __launch_bounds__(256) void gemm_oproj(
    const unsigned short* __restrict__ A,
    const unsigned short* __restrict__ W,
    float* __restrict__ out)
{
  const int n0 = blockIdx.x * 64;
  const int m0 = blockIdx.y * 128;

  __shared__ unsigned short As0[128 * 32];
  __shared__ unsigned short As1[128 * 32];
  __shared__ unsigned short Bs0[64 * 32];
  __shared__ unsigned short Bs1[64 * 32];

  const int tid  = threadIdx.x;
  const int wid  = tid >> 6, lane = tid & 63;
  const int wm   = (wid >> 1) * 64, wn = (wid & 1) * 32;
  const int lr   = lane & 15, lk = (lane >> 4) * 8;

  const int srow = lane >> 2;
  const int scol = (lane & 3) * 8;
  const unsigned short* gA = A + (size_t)(m0 + wid * 32 + srow) * KDIM + scol;
  const unsigned short* gB = W + (size_t)(n0 + wid * 16 + srow) * KDIM + scol;
  unsigned short* lA0 = &As0[(wid * 32) * 32];
  unsigned short* lA1 = &As1[(wid * 32) * 32];
  unsigned short* lB0 = &Bs0[(wid * 16) * 32];
  unsigned short* lB1 = &Bs1[(wid * 16) * 32];

  f32x4 acc[4][2];
  const f32x4 z4 = {0.f, 0.f, 0.f, 0.f};
  for (int i = 0; i < 4; i++)
    for (int j = 0; j < 2; j++) acc[i][j] = z4;

  for (int k0 = 0; k0 < KDIM; k0 += 64) {
    __syncthreads();
    gll16(gA + k0,                  lA0);
    gll16(gA + 16 * KDIM + k0,      lA0 + 16 * 32);
    gll16(gA + k0 + 32,             lA1);
    gll16(gA + 16 * KDIM + k0 + 32, lA1 + 16 * 32);
    gll16(gB + k0,                  lB0);
    gll16(gB + k0 + 32,             lB1);
    __syncthreads();

    short8 a[4], b[2];
    for (int i = 0; i < 4; i++) a[i] = *(const short8*)&As0[(wm + i * 16 + lr) * 32 + lk];
    for (int j = 0; j < 2; j++) b[j] = *(const short8*)&Bs0[(wn + j * 16 + lr) * 32 + lk];
    for (int i = 0; i < 4; i++)
      for (int j = 0; j < 2; j++)
        acc[i][j] = MFMA(a[i], b[j], acc[i][j]);
    for (int i = 0; i < 4; i++) a[i] = *(const short8*)&As1[(wm + i * 16 + lr) * 32 + lk];
    for (int j = 0; j < 2; j++) b[j] = *(const short8*)&Bs1[(wn + j * 16 + lr) * 32 + lk];
    for (int i = 0; i < 4; i++)
      for (int j = 0; j < 2; j++)
        acc[i][j] = MFMA(a[i], b[j], acc[i][j]);
  }

  const int rbase = (lane >> 4) * 4;
  for (int i = 0; i < 4; i++)
    for (int j = 0; j < 2; j++)
      for (int r = 0; r < 4; r++) {
        int m = m0 + wm + i * 16 + rbase + r;
        int n = n0 + wn + j * 16 + lr;
        out[(size_t)m * D_ + n] = acc[i][j][r];
      }
}

extern "C" void kernel_launch(void* const* d_in, const int* in_sizes, int n_in,
                              void* d_out, int out_size, void* d_ws, size_t ws_size,
                              hipStream_t stream) {
  const float* x  = (const float*)d_in[0];
  const float* qw = (const float*)d_in[1];
  const float* kw = (const float*)d_in[2];
  const float* vw = (const float*)d_in[3];
  const float* ow = (const float*)d_in[4];
  float* out = (float*)d_out;

  char* ws = (char*)d_ws;
  size_t off = 0;
  auto alloc = [&](size_t bytes) -> void* {
    void* p = ws + off;
    off += (bytes + 255) & ~(size_t)255;
    return p;
  };
  const size_t XN = (size_t)B_ * S_ * D_;     // 4194304
  const size_t WN = (size_t)D_ * D_;          // 1048576
  unsigned short* xb  = (unsigned short*)alloc(XN * 2);
  unsigned short* wqb = (unsigned short*)alloc(WN * 2);
  unsigned short* wkb = (unsigned short*)alloc(WN * 2);
  unsigned short* wvb = (unsigned short*)alloc(WN * 2);
  unsigned short* wob = (unsigned short*)alloc(WN * 2);
  unsigned short* Qb  = (unsigned short*)alloc(XN * 2);
  unsigned short* Kb  = (unsigned short*)alloc(XN * 2);
  unsigned short* Vb  = (unsigned short*)alloc(XN * 2);
  unsigned short* Ob  = (unsigned short*)alloc(XN * 2);

  cvt_all<<<dim3((XN / 4 + 255) / 256, 5), dim3(256), 0, stream>>>(
      x, qw, kw, vw, ow, xb, wqb, wkb, wvb, wob, (int)(XN / 4), (int)(WN / 4));

  gemm_qkv<<<dim3(D_ / 64, (B_ * S_) / 128, 3), dim3(256), 0, stream>>>(
      xb, wqb, wkb, wvb, Qb, Kb, Vb);

  attn<<<dim3(S_ / 128, H_, B_), dim3(512), 0, stream>>>(Qb, Kb, Vb, Ob);

  gemm_oproj<<<dim3(D_ / 64, (B_ * S_) / 128), dim3(256), 0, stream>>>(Ob, wob, out);
}